// Round 5
// baseline (352.114 us; speedup 1.0000x reference)
//
#include <hip/hip_runtime.h>
#include <math.h>
#include <stdint.h>

#define C        128
#define KCODES   1024
#define KHALF    512                  // codes per k-split block
#define TPB      256
#define ROWS_PB  128                  // rows per block
#define NCHUNK   64                   // codes per LDS chunk
#define NCHUNKS_H (KHALF / NCHUNK)    // 8 chunks per half
#define BSTRIDE  272                  // padded row stride (bytes) = 128*2 + 16
#define BHALF    (NCHUNK * BSTRIDE)   // byte offset of the LO plane
#define EPS_TRIG 0.25f

typedef __attribute__((ext_vector_type(8))) short bf16x8_t;
typedef __attribute__((ext_vector_type(4))) float f32x4_t;

static __device__ __forceinline__ uint32_t bf16_rne(float f) {
    uint32_t u = __float_as_uint(f);
    return (u + 0x7FFFu + ((u >> 16) & 1u)) >> 16;
}
static __device__ __forceinline__ float bf16_hi_f(float f) {
    return __uint_as_float(bf16_rne(f) << 16);
}

// ============================================================================
// Fully fused kernel: inline cb->bf16 hi/lo conversion + MFMA distance +
// per-half top-2 + last-block-of-pair finalize.
//   grid = 2 * rowblocks; block (rb, kh) scans codes [kh*512, +512) for rows
//   [rb*128, +128).  The SECOND block of each (rb) pair to finish (parity
//   atomicAdd; works with or without workspace zeroing) merges both halves
//   and runs the exact finalize + gather for those 128 rows (x/cb L2-hot).
// Launch overhead was ~20us/launch -> 1 launch instead of 3 saves ~40us.
// ============================================================================
#define SLOTS(OP) OP(0,0) OP(0,1) OP(0,2) OP(0,3) OP(1,0) OP(1,1) OP(1,2) OP(1,3)
#define MFMA_BF16 __builtin_amdgcn_mfma_f32_16x16x32_bf16

__global__ __launch_bounds__(TPB, 3)
void vq_fused_kernel(const float* __restrict__ x,
                     const float* __restrict__ cb,
                     unsigned long long* __restrict__ top2,  // [2][rows][2] u64: (f32bits<<32)|k
                     unsigned int* __restrict__ cnt,         // [rowblocks] parity counters
                     float* __restrict__ out_codes,
                     float* __restrict__ out_fidx,
                     float* __restrict__ out_idx,
                     float* __restrict__ out_dist,
                     int rows)
{
    __shared__ __align__(16) uint8_t s_buf[2 * BHALF];   // 34816 B, also A-stage area
    __shared__ float s_cq[NCHUNK];
    __shared__ int   s_k1f[ROWS_PB];
    __shared__ int   s_win;

    const int t    = threadIdx.x;
    const int lane = t & 63;
    const int w    = t >> 6;       // wave 0..3
    const int ln   = lane & 15;
    const int quad = lane >> 4;
    const int rb   = blockIdx.x >> 1;
    const int kh   = blockIdx.x & 1;
    const int rowblock = rb * ROWS_PB;
    const int kh0      = kh * KHALF;

    // ---- stage x tile -> bf16 HI in s_buf (padded row-major) ----
    #pragma unroll 4
    for (int i = 0; i < 16; ++i) {
        int fid = t + i * TPB;            // float4 id in tile (4096)
        int row = fid >> 5;               // 0..127
        int kq  = fid & 31;               // float4 within row
        int grow = rowblock + row;
        grow = grow < rows ? grow : rows - 1;
        float4 v = ((const float4*)x)[(size_t)grow * 32 + kq];
        uint32_t p0 = bf16_rne(v.x) | (bf16_rne(v.y) << 16);
        uint32_t p1 = bf16_rne(v.z) | (bf16_rne(v.w) << 16);
        *(uint2*)(s_buf + row * BSTRIDE + kq * 8) = make_uint2(p0, p1);
    }
    __syncthreads();

    // ---- A-hi fragments -> registers (live for the whole kernel) ----
    const int arow0 = (w * 32 + ln) * BSTRIDE;        // rowgroup 0
    const int arow1 = (w * 32 + 16 + ln) * BSTRIDE;   // rowgroup 1
    bf16x8_t ah00, ah01, ah02, ah03, ah10, ah11, ah12, ah13;
    ah00 = *(const bf16x8_t*)(s_buf + arow0 + 0 * 64 + quad * 16);
    ah01 = *(const bf16x8_t*)(s_buf + arow0 + 1 * 64 + quad * 16);
    ah02 = *(const bf16x8_t*)(s_buf + arow0 + 2 * 64 + quad * 16);
    ah03 = *(const bf16x8_t*)(s_buf + arow0 + 3 * 64 + quad * 16);
    ah10 = *(const bf16x8_t*)(s_buf + arow1 + 0 * 64 + quad * 16);
    ah11 = *(const bf16x8_t*)(s_buf + arow1 + 1 * 64 + quad * 16);
    ah12 = *(const bf16x8_t*)(s_buf + arow1 + 2 * 64 + quad * 16);
    ah13 = *(const bf16x8_t*)(s_buf + arow1 + 3 * 64 + quad * 16);
    __syncthreads();

    // ---- stage x tile -> bf16 LO ----
    #pragma unroll 4
    for (int i = 0; i < 16; ++i) {
        int fid = t + i * TPB;
        int row = fid >> 5;
        int kq  = fid & 31;
        int grow = rowblock + row;
        grow = grow < rows ? grow : rows - 1;
        float4 v = ((const float4*)x)[(size_t)grow * 32 + kq];
        uint32_t p0 = bf16_rne(v.x - bf16_hi_f(v.x)) | (bf16_rne(v.y - bf16_hi_f(v.y)) << 16);
        uint32_t p1 = bf16_rne(v.z - bf16_hi_f(v.z)) | (bf16_rne(v.w - bf16_hi_f(v.w)) << 16);
        *(uint2*)(s_buf + row * BSTRIDE + kq * 8) = make_uint2(p0, p1);
    }
    __syncthreads();

    bf16x8_t al00, al01, al02, al03, al10, al11, al12, al13;
    al00 = *(const bf16x8_t*)(s_buf + arow0 + 0 * 64 + quad * 16);
    al01 = *(const bf16x8_t*)(s_buf + arow0 + 1 * 64 + quad * 16);
    al02 = *(const bf16x8_t*)(s_buf + arow0 + 2 * 64 + quad * 16);
    al03 = *(const bf16x8_t*)(s_buf + arow0 + 3 * 64 + quad * 16);
    al10 = *(const bf16x8_t*)(s_buf + arow1 + 0 * 64 + quad * 16);
    al11 = *(const bf16x8_t*)(s_buf + arow1 + 1 * 64 + quad * 16);
    al12 = *(const bf16x8_t*)(s_buf + arow1 + 2 * 64 + quad * 16);
    al13 = *(const bf16x8_t*)(s_buf + arow1 + 3 * 64 + quad * 16);
    __syncthreads();

    // ---- per-lane top-2 state (8 row-slots) ----
#define DECL(g,r) float v1_##g##r = INFINITY, v2_##g##r = INFINITY; int k1_##g##r = 0, k2_##g##r = 0;
    SLOTS(DECL)
#undef DECL

    #pragma unroll 1
    for (int chn = 0; chn < NCHUNKS_H; ++chn) {
        const int kbase = kh0 + chn * NCHUNK;
        // ---- stage B chunk from RAW fp32 codebook: convert bf16 hi/lo inline
        //      (bit-identical exprs to the old cb_split_kernel) + coarse ||c||^2
        //      via 16-lane reduce (coarse-only: feeds top-2 selection, and
        //      boundary rows never switch, so outputs are unaffected). ----
        #pragma unroll
        for (int i = 0; i < 4; ++i) {
            int uid  = t + i * TPB;          // slot id (1024): code*16 + g
            int code = uid >> 4, g = uid & 15;
            const float4* src = (const float4*)(cb + (size_t)(kbase + code) * C) + g * 2;
            float4 v0 = src[0], v1 = src[1];
            uint32_t h0 = bf16_rne(v0.x) | (bf16_rne(v0.y) << 16);
            uint32_t h1 = bf16_rne(v0.z) | (bf16_rne(v0.w) << 16);
            uint32_t h2 = bf16_rne(v1.x) | (bf16_rne(v1.y) << 16);
            uint32_t h3 = bf16_rne(v1.z) | (bf16_rne(v1.w) << 16);
            uint32_t l0 = bf16_rne(v0.x - bf16_hi_f(v0.x)) | (bf16_rne(v0.y - bf16_hi_f(v0.y)) << 16);
            uint32_t l1 = bf16_rne(v0.z - bf16_hi_f(v0.z)) | (bf16_rne(v0.w - bf16_hi_f(v0.w)) << 16);
            uint32_t l2 = bf16_rne(v1.x - bf16_hi_f(v1.x)) | (bf16_rne(v1.y - bf16_hi_f(v1.y)) << 16);
            uint32_t l3 = bf16_rne(v1.z - bf16_hi_f(v1.z)) | (bf16_rne(v1.w - bf16_hi_f(v1.w)) << 16);
            *(uint4*)(s_buf + code * BSTRIDE + g * 16)          = make_uint4(h0, h1, h2, h3);
            *(uint4*)(s_buf + BHALF + code * BSTRIDE + g * 16)  = make_uint4(l0, l1, l2, l3);
            float ps = ((v0.x * v0.x + v0.y * v0.y) + (v0.z * v0.z + v0.w * v0.w))
                     + ((v1.x * v1.x + v1.y * v1.y) + (v1.z * v1.z + v1.w * v1.w));
            ps += __shfl_xor(ps, 1, 16);
            ps += __shfl_xor(ps, 2, 16);
            ps += __shfl_xor(ps, 4, 16);
            ps += __shfl_xor(ps, 8, 16);
            if (g == 0) s_cq[code] = ps;
        }
        __syncthreads();

        const uint8_t* bbase = s_buf + (size_t)ln * BSTRIDE + quad * 16;
        #pragma unroll
        for (int ct = 0; ct < 4; ++ct) {
            const uint8_t* bh_p = bbase + (size_t)ct * 16 * BSTRIDE;
            const uint8_t* bl_p = bh_p + BHALF;
            f32x4_t acc0 = {0.f, 0.f, 0.f, 0.f};
            f32x4_t acc1 = {0.f, 0.f, 0.f, 0.f};
#define KSTEP(kk) { \
            bf16x8_t bh = *(const bf16x8_t*)(bh_p + kk * 64); \
            bf16x8_t bl = *(const bf16x8_t*)(bl_p + kk * 64); \
            acc0 = MFMA_BF16(ah0##kk, bh, acc0, 0, 0, 0); \
            acc0 = MFMA_BF16(al0##kk, bh, acc0, 0, 0, 0); \
            acc0 = MFMA_BF16(ah0##kk, bl, acc0, 0, 0, 0); \
            acc1 = MFMA_BF16(ah1##kk, bh, acc1, 0, 0, 0); \
            acc1 = MFMA_BF16(al1##kk, bh, acc1, 0, 0, 0); \
            acc1 = MFMA_BF16(ah1##kk, bl, acc1, 0, 0, 0); }
            KSTEP(0) KSTEP(1) KSTEP(2) KSTEP(3)
#undef KSTEP
            const float cqv = s_cq[ct * 16 + ln];
            const int   kc  = kbase + ct * 16 + ln;
#define UPD(g,r) { \
            float s_ = fmaf(-2.0f, (g ? acc1 : acc0)[r], cqv); \
            bool c1_ = s_ < v1_##g##r; \
            bool c2_ = s_ < v2_##g##r; \
            v2_##g##r = c1_ ? v1_##g##r : (c2_ ? s_ : v2_##g##r); \
            k2_##g##r = c1_ ? k1_##g##r : (c2_ ? kc : k2_##g##r); \
            v1_##g##r = c1_ ? s_ : v1_##g##r; \
            k1_##g##r = c1_ ? kc : k1_##g##r; }
            SLOTS(UPD)
#undef UPD
        }
        __syncthreads();
    }

    // ---- butterfly merge across the 16 lanes of each col-group ----
    for (int m_ = 1; m_ <= 8; m_ <<= 1) {
#define MRG(g,r) { \
        float ov1 = __shfl_xor(v1_##g##r, m_, 16); int ok1 = __shfl_xor(k1_##g##r, m_, 16); \
        float ov2 = __shfl_xor(v2_##g##r, m_, 16); int ok2 = __shfl_xor(k2_##g##r, m_, 16); \
        if (ov1 < v1_##g##r || (ov1 == v1_##g##r && ok1 < k1_##g##r)) { \
            if (v1_##g##r < ov2 || (v1_##g##r == ov2 && k1_##g##r < ok2)) { v2_##g##r = v1_##g##r; k2_##g##r = k1_##g##r; } \
            else { v2_##g##r = ov2; k2_##g##r = ok2; } \
            v1_##g##r = ov1; k1_##g##r = ok1; \
        } else if (ov1 < v2_##g##r || (ov1 == v2_##g##r && ok1 < k2_##g##r)) { \
            v2_##g##r = ov1; k2_##g##r = ok1; \
        } }
        SLOTS(MRG)
#undef MRG
    }
    // ---- lane 0 of each col-group publishes per-row top-2 (device scope) ----
    if (ln == 0) {
#define WRT(g,r) { int rloc = w * 32 + g * 16 + quad * 4 + r; \
        int rowg = rowblock + rloc; \
        if (rowg < rows) { \
            size_t base_ = ((size_t)kh * rows + rowg) << 1; \
            unsigned long long e1 = ((unsigned long long)__float_as_uint(v1_##g##r) << 32) | (unsigned)k1_##g##r; \
            unsigned long long e2 = ((unsigned long long)__float_as_uint(v2_##g##r) << 32) | (unsigned)k2_##g##r; \
            __hip_atomic_store(&top2[base_ + 0], e1, __ATOMIC_RELAXED, __HIP_MEMORY_SCOPE_AGENT); \
            __hip_atomic_store(&top2[base_ + 1], e2, __ATOMIC_RELAXED, __HIP_MEMORY_SCOPE_AGENT); } }
        SLOTS(WRT)
#undef WRT
    }
    __syncthreads();   // all lanes' top2 stores drained (vmcnt 0 before barrier)

    // ---- completion detection: second finisher of the (rb) pair finalizes.
    //      Parity works whether or not the workspace is zeroed between runs. ----
    if (t == 0) {
        __threadfence();                               // release
        unsigned old = atomicAdd(&cnt[rb], 1u);        // device-scope
        s_win = (int)(old & 1u);
    }
    __syncthreads();
    if (!s_win) return;
    __threadfence();                                   // acquire

    // ======================= finalize (winner only) ========================
    if (t < ROWS_PB) {
        int rowg = rowblock + t;
        const bool valid = rowg < rows;
        rowg = valid ? rowg : rows - 1;

        unsigned long long ea1 = __hip_atomic_load(&top2[((size_t)rowg << 1) + 0], __ATOMIC_RELAXED, __HIP_MEMORY_SCOPE_AGENT);
        unsigned long long ea2 = __hip_atomic_load(&top2[((size_t)rowg << 1) + 1], __ATOMIC_RELAXED, __HIP_MEMORY_SCOPE_AGENT);
        unsigned long long eb1 = __hip_atomic_load(&top2[(((size_t)rows + rowg) << 1) + 0], __ATOMIC_RELAXED, __HIP_MEMORY_SCOPE_AGENT);
        unsigned long long eb2 = __hip_atomic_load(&top2[(((size_t)rows + rowg) << 1) + 1], __ATOMIC_RELAXED, __HIP_MEMORY_SCOPE_AGENT);
        float av1 = __uint_as_float((uint32_t)(ea1 >> 32)); int ak1 = (int)(uint32_t)ea1;
        float av2 = __uint_as_float((uint32_t)(ea2 >> 32)); int ak2 = (int)(uint32_t)ea2;
        float bv1 = __uint_as_float((uint32_t)(eb1 >> 32)); int bk1 = (int)(uint32_t)eb1;
        float bv2 = __uint_as_float((uint32_t)(eb2 >> 32)); int bk2 = (int)(uint32_t)eb2;

        // merge the two halves' top-2 (same comparator as MRG; half-0 indices
        // < half-1 indices, so index-tiebreak == sequential-scan order)
        float v1, v2; int k1, k2;
        if (bv1 < av1 || (bv1 == av1 && bk1 < ak1)) {
            v1 = bv1; k1 = bk1;
            if (av1 < bv2 || (av1 == bv2 && ak1 < bk2)) { v2 = av1; k2 = ak1; }
            else                                        { v2 = bv2; k2 = bk2; }
        } else {
            v1 = av1; k1 = ak1;
            if (bv1 < av2 || (bv1 == av2 && bk1 < ak2)) { v2 = bv1; k2 = bk1; }
            else                                        { v2 = av2; k2 = ak2; }
        }

        const float* xr = x + (size_t)rowg * C;

        // rs in R1 float4 order
        float sx = 0.f, sy = 0.f, sz = 0.f, sw = 0.f;
        {
            const float4* xp = (const float4*)xr;
            #pragma unroll
            for (int i = 0; i < C / 4; ++i) {
                float4 v = xp[i];
                sx += v.x * v.x; sy += v.y * v.y;
                sz += v.z * v.z; sw += v.w * v.w;
            }
        }
        const float rs = (sx + sy) + (sz + sw);

        bool switched = false;
        double qwin = 0.0;
        if (v2 - v1 < EPS_TRIG) {
            const float* c1p = cb + (size_t)k1 * C;
            const float* c2p = cb + (size_t)k2 * C;
            double dot1 = 0.0, cq1 = 0.0, dot2 = 0.0, cq2 = 0.0;
            #pragma unroll 8
            for (int c = 0; c < C; ++c) {
                const double xc  = (double)xr[c];
                const double cv1 = (double)c1p[c];
                const double cv2 = (double)c2p[c];
                dot1 += xc * cv1;  cq1 += cv1 * cv1;
                dot2 += xc * cv2;  cq2 += cv2 * cv2;
            }
            const double q1 = cq1 - 2.0 * dot1;
            const double q2 = cq2 - 2.0 * dot2;
            if (q2 < q1 || (q2 == q1 && k2 < k1)) { k1 = k2; switched = true; qwin = q2; }
        }

        // exact fp32 distance for the final k1 (R1 chain order) + inline
        // ||c_k1||^2 in the exact cbsq_kernel float4 order (bit-identical)
        {
            const float4* c1p4 = (const float4*)(cb + (size_t)k1 * C);
            const float4* xp4  = (const float4*)xr;
            float a = 0.f;
            float qx = 0.f, qy = 0.f, qz = 0.f, qw = 0.f;
            #pragma unroll
            for (int i = 0; i < C / 4; ++i) {
                float4 cv = c1p4[i]; float4 xv = xp4[i];
                a = fmaf(xv.x, cv.x, a); a = fmaf(xv.y, cv.y, a);
                a = fmaf(xv.z, cv.z, a); a = fmaf(xv.w, cv.w, a);
                qx += cv.x * cv.x; qy += cv.y * cv.y;
                qz += cv.z * cv.z; qw += cv.w * cv.w;
            }
            float d = (rs + ((qx + qy) + (qz + qw))) - 2.f * a;
            if (switched) d = (float)((double)rs + qwin);

            if (valid) {
                out_fidx[rowg] = (float)k1;
                out_idx[rowg]  = (float)k1;
                out_dist[rowg] = d;
            }
        }
        s_k1f[t] = k1;   // final index for the gather
    }
    __syncthreads();

    // ---- gather codes: 2 threads per row ----
    {
        const int r    = t >> 1;
        const int half = t & 1;
        const int rowg = rowblock + r;
        if (rowg < rows) {
            const int k1 = s_k1f[r];
            const float4* src = (const float4*)(cb + (size_t)k1 * C) + half * 16;
            float4*       dst = (float4*)(out_codes + (size_t)rowg * C) + half * 16;
            #pragma unroll
            for (int i = 0; i < 16; ++i) dst[i] = src[i];
        }
    }
}

// ---------------- fallback (R1 kernel, needs no workspace) ----------------
__global__ __launch_bounds__(TPB, 1)
void vq_nearest_fallback(const float* __restrict__ x,
                         const float* __restrict__ cb,
                         float* __restrict__ out_codes,
                         float* __restrict__ out_fidx,
                         float* __restrict__ out_idx,
                         float* __restrict__ out_dist,
                         int rows)
{
    __shared__ float s_cbsq[KCODES];
    const int t = threadIdx.x;
    for (int k = t; k < KCODES; k += TPB) {
        const float4* cp = (const float4*)(cb + (size_t)k * C);
        float sx = 0.f, sy = 0.f, sz = 0.f, sw = 0.f;
        #pragma unroll
        for (int i = 0; i < C / 4; ++i) {
            float4 v = cp[i];
            sx += v.x * v.x; sy += v.y * v.y; sz += v.z * v.z; sw += v.w * v.w;
        }
        s_cbsq[k] = (sx + sy) + (sz + sw);
    }
    __syncthreads();
    const int row = blockIdx.x * TPB + t;
    if (row >= rows) return;
    float xr[C];
    {
        const float4* xp = (const float4*)(x + (size_t)row * C);
        #pragma unroll
        for (int i = 0; i < C / 4; ++i) {
            float4 v = xp[i];
            xr[4*i+0] = v.x; xr[4*i+1] = v.y; xr[4*i+2] = v.z; xr[4*i+3] = v.w;
        }
    }
    float rs;
    {
        float sx = 0.f, sy = 0.f, sz = 0.f, sw = 0.f;
        #pragma unroll
        for (int i = 0; i < C / 4; ++i) {
            sx += xr[4*i+0]*xr[4*i+0]; sy += xr[4*i+1]*xr[4*i+1];
            sz += xr[4*i+2]*xr[4*i+2]; sw += xr[4*i+3]*xr[4*i+3];
        }
        rs = (sx + sy) + (sz + sw);
    }
    float v1 = INFINITY, v2 = INFINITY; int k1 = 0, k2 = 0;
    #pragma unroll 1
    for (int k0 = 0; k0 < KCODES; k0 += 4) {
        const float* c0 = cb + (size_t)k0 * C;
        float a0 = 0.f, a1 = 0.f, a2 = 0.f, a3 = 0.f;
        #pragma unroll
        for (int c = 0; c < C; ++c) {
            const float xc = xr[c];
            a0 = fmaf(xc, c0[c], a0);
            a1 = fmaf(xc, c0[C + c], a1);
            a2 = fmaf(xc, c0[2*C + c], a2);
            a3 = fmaf(xc, c0[3*C + c], a3);
        }
        const float d0 = (rs + s_cbsq[k0+0]) - 2.f * a0;
        const float d1 = (rs + s_cbsq[k0+1]) - 2.f * a1;
        const float d2 = (rs + s_cbsq[k0+2]) - 2.f * a2;
        const float d3 = (rs + s_cbsq[k0+3]) - 2.f * a3;
        #define UPDF(dv, ki)                                                 \
            if ((dv) < v1)      { v2 = v1; k2 = k1; v1 = (dv); k1 = (ki); } \
            else if ((dv) < v2) { v2 = (dv); k2 = (ki); }
        UPDF(d0, k0+0); UPDF(d1, k0+1); UPDF(d2, k0+2); UPDF(d3, k0+3);
        #undef UPDF
    }
    if (v2 - v1 < 0.125f) {
        const float* c1p = cb + (size_t)k1 * C;
        const float* c2p = cb + (size_t)k2 * C;
        double dot1 = 0.0, cq1 = 0.0, dot2 = 0.0, cq2 = 0.0;
        #pragma unroll 8
        for (int c = 0; c < C; ++c) {
            const double xc = (double)xr[c];
            const double cv1 = (double)c1p[c];
            const double cv2 = (double)c2p[c];
            dot1 += xc * cv1; cq1 += cv1 * cv1;
            dot2 += xc * cv2; cq2 += cv2 * cv2;
        }
        const double q1 = cq1 - 2.0 * dot1;
        const double q2 = cq2 - 2.0 * dot2;
        if (q2 < q1 || (q2 == q1 && k2 < k1)) { k1 = k2; v1 = (float)((double)rs + q2); }
    }
    {
        const float4* src = (const float4*)(cb + (size_t)k1 * C);
        float4* dst = (float4*)(out_codes + (size_t)row * C);
        #pragma unroll
        for (int i = 0; i < C / 4; ++i) dst[i] = src[i];
        out_fidx[row] = (float)k1;
        out_idx[row]  = (float)k1;
        out_dist[row] = v1;
    }
}

extern "C" void kernel_launch(void* const* d_in, const int* in_sizes, int n_in,
                              void* d_out, int out_size, void* d_ws, size_t ws_size,
                              hipStream_t stream) {
    const float* x  = (const float*)d_in[0];
    const float* cb = (const float*)d_in[1];
    const int rows = in_sizes[0] / C;   // 65536

    float* out       = (float*)d_out;
    float* out_codes = out;                          // rows*C
    float* out_fidx  = out + (size_t)rows * C;       // rows
    float* out_idx   = out_fidx + rows;              // rows
    float* out_dist  = out_idx + rows;               // rows

    const int rowblocks = (rows + ROWS_PB - 1) / ROWS_PB;              // 512

    // workspace layout: top2 [2][rows][2] u64 + parity counters
    const size_t top2_off = 0;
    const size_t cnt_off  = (size_t)2 * rows * 2 * sizeof(unsigned long long); // 2 MB
    const size_t need     = cnt_off + (size_t)rowblocks * sizeof(unsigned int);

    if (ws_size >= need) {
        unsigned long long* top2 = (unsigned long long*)((char*)d_ws + top2_off);
        unsigned int*       cnt  = (unsigned int*)((char*)d_ws + cnt_off);

        vq_fused_kernel<<<rowblocks * 2, TPB, 0, stream>>>(x, cb, top2, cnt,
                                                           out_codes, out_fidx,
                                                           out_idx, out_dist, rows);
    } else {
        const int rb = (rows + TPB - 1) / TPB;
        vq_nearest_fallback<<<rb, TPB, 0, stream>>>(x, cb, out_codes, out_fidx,
                                                    out_idx, out_dist, rows);
    }
}

// Round 6
// 238.874 us; speedup vs baseline: 1.4741x; 1.4741x over previous
//
#include <hip/hip_runtime.h>
#include <math.h>
#include <stdint.h>

#define C        128
#define KCODES   1024
#define TPB      256
#define ROWS_PB  128                  // rows per block
#define NKT      (KCODES / 16)        // 64 B-tiles of 16 codes
#define BSTRIDE  272                  // padded A row stride (bytes) = 128*2 + 16
#define EPS_TRIG 0.25f

typedef __attribute__((ext_vector_type(8))) short bf16x8_t;
typedef __attribute__((ext_vector_type(4))) float f32x4_t;

static __device__ __forceinline__ uint32_t bf16_rne(float f) {
    uint32_t u = __float_as_uint(f);
    return (u + 0x7FFFu + ((u >> 16) & 1u)) >> 16;
}
static __device__ __forceinline__ float bf16_hi_f(float f) {
    return __uint_as_float(bf16_rne(f) << 16);
}

// ---------------- prep (fused): split codebook into bf16 hi/lo + ||c||^2 ----------------
// Run ONCE per launch (R5 lesson: re-converting per block + device-scope fences
// cost far more than one extra ~20us kernel launch).
__global__ void cb_prep_kernel(const float* __restrict__ cb,
                               uint16_t* __restrict__ cbh,
                               uint16_t* __restrict__ cbl,
                               float* __restrict__ cbsq) {
    const int i = blockIdx.x * blockDim.x + threadIdx.x;
    if (i < KCODES * C) {
        float f = cb[i];
        uint32_t h = bf16_rne(f);
        float lo = f - __uint_as_float(h << 16);
        cbh[i] = (uint16_t)h;
        cbl[i] = (uint16_t)bf16_rne(lo);
    }
    if (i < KCODES) {
        const float4* cp = (const float4*)(cb + (size_t)i * C);
        float sx = 0.f, sy = 0.f, sz = 0.f, sw = 0.f;
        #pragma unroll
        for (int j = 0; j < C / 4; ++j) {
            float4 v = cp[j];
            sx += v.x * v.x; sy += v.y * v.y;
            sz += v.z * v.z; sw += v.w * v.w;
        }
        cbsq[i] = (sx + sy) + (sz + sw);
    }
}

// ============================================================================
// Main kernel, barrier-free K-loop:
//   - A tile (128 rows) staged in LDS once (hi then lo), held in registers.
//   - B fragments loaded DIRECTLY from global (cbh/cbl are 512KB total: fully
//     L2-resident per XCD; all 4 waves of a block read identical addresses ->
//     L1-shared). No B staging, no ds_write, no __syncthreads in the K-loop.
//     (Common-mistake #7: don't LDS-stage what the cache already holds.)
//   - Manual 2-deep load pipeline with NAMED register sets (rule #20: no
//     runtime-indexed arrays).
//   - In-block finalize + gather (R1 structure, bit-identical numerics).
// ============================================================================
#define SLOTS(OP) OP(0,0) OP(0,1) OP(0,2) OP(0,3) OP(1,0) OP(1,1) OP(1,2) OP(1,3)
#define MFMA_BF16 __builtin_amdgcn_mfma_f32_16x16x32_bf16

__global__ __launch_bounds__(TPB, 2)
void vq_mfma_kernel(const float* __restrict__ x,
                    const float* __restrict__ cb,
                    const uint16_t* __restrict__ cbh,
                    const uint16_t* __restrict__ cbl,
                    const float* __restrict__ cq,
                    float* __restrict__ out_codes,
                    float* __restrict__ out_fidx,
                    float* __restrict__ out_idx,
                    float* __restrict__ out_dist,
                    int rows)
{
    __shared__ __align__(16) uint8_t s_buf[ROWS_PB * BSTRIDE];   // 34816 B: A staging only
    __shared__ float s_v1[ROWS_PB], s_v2[ROWS_PB];
    __shared__ int   s_k1[ROWS_PB], s_k2[ROWS_PB];

    const int t    = threadIdx.x;
    const int lane = t & 63;
    const int w    = t >> 6;       // wave 0..3
    const int ln   = lane & 15;
    const int quad = lane >> 4;
    const int rowblock = blockIdx.x * ROWS_PB;

    // ---- stage x tile -> bf16 HI in s_buf (padded row-major) ----
    #pragma unroll 4
    for (int i = 0; i < 16; ++i) {
        int fid = t + i * TPB;            // float4 id in tile (4096)
        int row = fid >> 5;               // 0..127
        int kq  = fid & 31;               // float4 within row
        int grow = rowblock + row;
        grow = grow < rows ? grow : rows - 1;
        float4 v = ((const float4*)x)[(size_t)grow * 32 + kq];
        uint32_t p0 = bf16_rne(v.x) | (bf16_rne(v.y) << 16);
        uint32_t p1 = bf16_rne(v.z) | (bf16_rne(v.w) << 16);
        *(uint2*)(s_buf + row * BSTRIDE + kq * 8) = make_uint2(p0, p1);
    }
    __syncthreads();

    // ---- A-hi fragments -> registers (live for the whole kernel) ----
    const int arow0 = (w * 32 + ln) * BSTRIDE;        // rowgroup 0
    const int arow1 = (w * 32 + 16 + ln) * BSTRIDE;   // rowgroup 1
    bf16x8_t ah00, ah01, ah02, ah03, ah10, ah11, ah12, ah13;
    ah00 = *(const bf16x8_t*)(s_buf + arow0 + 0 * 64 + quad * 16);
    ah01 = *(const bf16x8_t*)(s_buf + arow0 + 1 * 64 + quad * 16);
    ah02 = *(const bf16x8_t*)(s_buf + arow0 + 2 * 64 + quad * 16);
    ah03 = *(const bf16x8_t*)(s_buf + arow0 + 3 * 64 + quad * 16);
    ah10 = *(const bf16x8_t*)(s_buf + arow1 + 0 * 64 + quad * 16);
    ah11 = *(const bf16x8_t*)(s_buf + arow1 + 1 * 64 + quad * 16);
    ah12 = *(const bf16x8_t*)(s_buf + arow1 + 2 * 64 + quad * 16);
    ah13 = *(const bf16x8_t*)(s_buf + arow1 + 3 * 64 + quad * 16);
    __syncthreads();

    // ---- stage x tile -> bf16 LO ----
    #pragma unroll 4
    for (int i = 0; i < 16; ++i) {
        int fid = t + i * TPB;
        int row = fid >> 5;
        int kq  = fid & 31;
        int grow = rowblock + row;
        grow = grow < rows ? grow : rows - 1;
        float4 v = ((const float4*)x)[(size_t)grow * 32 + kq];
        uint32_t p0 = bf16_rne(v.x - bf16_hi_f(v.x)) | (bf16_rne(v.y - bf16_hi_f(v.y)) << 16);
        uint32_t p1 = bf16_rne(v.z - bf16_hi_f(v.z)) | (bf16_rne(v.w - bf16_hi_f(v.w)) << 16);
        *(uint2*)(s_buf + row * BSTRIDE + kq * 8) = make_uint2(p0, p1);
    }
    __syncthreads();

    bf16x8_t al00, al01, al02, al03, al10, al11, al12, al13;
    al00 = *(const bf16x8_t*)(s_buf + arow0 + 0 * 64 + quad * 16);
    al01 = *(const bf16x8_t*)(s_buf + arow0 + 1 * 64 + quad * 16);
    al02 = *(const bf16x8_t*)(s_buf + arow0 + 2 * 64 + quad * 16);
    al03 = *(const bf16x8_t*)(s_buf + arow0 + 3 * 64 + quad * 16);
    al10 = *(const bf16x8_t*)(s_buf + arow1 + 0 * 64 + quad * 16);
    al11 = *(const bf16x8_t*)(s_buf + arow1 + 1 * 64 + quad * 16);
    al12 = *(const bf16x8_t*)(s_buf + arow1 + 2 * 64 + quad * 16);
    al13 = *(const bf16x8_t*)(s_buf + arow1 + 3 * 64 + quad * 16);
    __syncthreads();

    // ---- per-lane top-2 state (8 row-slots) ----
#define DECL(g,r) float v1_##g##r = INFINITY, v2_##g##r = INFINITY; int k1_##g##r = 0, k2_##g##r = 0;
    SLOTS(DECL)
#undef DECL

    // ---- barrier-free K-loop: B tiles (16 codes each) straight from global ----
    // lane's fragment base: code (kt*16 + ln), K-slice quad*8 within each kk
    const uint8_t* bh_lane = (const uint8_t*)cbh + (size_t)ln * 256 + quad * 16;
    const uint8_t* bl_lane = (const uint8_t*)cbl + (size_t)ln * 256 + quad * 16;

#define DECL_B(S) bf16x8_t bh##S##0, bh##S##1, bh##S##2, bh##S##3, \
                           bl##S##0, bl##S##1, bl##S##2, bl##S##3; float cqv##S;

#define LOAD_B(S, kt) { \
    const uint8_t* hp = bh_lane + (size_t)(kt) * 4096; \
    const uint8_t* lp = bl_lane + (size_t)(kt) * 4096; \
    bh##S##0 = *(const bf16x8_t*)(hp + 0 * 64); \
    bh##S##1 = *(const bf16x8_t*)(hp + 1 * 64); \
    bh##S##2 = *(const bf16x8_t*)(hp + 2 * 64); \
    bh##S##3 = *(const bf16x8_t*)(hp + 3 * 64); \
    bl##S##0 = *(const bf16x8_t*)(lp + 0 * 64); \
    bl##S##1 = *(const bf16x8_t*)(lp + 1 * 64); \
    bl##S##2 = *(const bf16x8_t*)(lp + 2 * 64); \
    bl##S##3 = *(const bf16x8_t*)(lp + 3 * 64); \
    cqv##S = cq[(kt) * 16 + ln]; }

    // per-kk MFMA order identical to the old KSTEP chain (bit-exact acc):
    // acc0: hh,lh,hl ; acc1: hh,lh,hl — for kk = 0..3 in order.
#define COMPUTE_B(S, kt) { \
    f32x4_t acc0 = {0.f, 0.f, 0.f, 0.f}; \
    f32x4_t acc1 = {0.f, 0.f, 0.f, 0.f}; \
    acc0 = MFMA_BF16(ah00, bh##S##0, acc0, 0, 0, 0); \
    acc0 = MFMA_BF16(al00, bh##S##0, acc0, 0, 0, 0); \
    acc0 = MFMA_BF16(ah00, bl##S##0, acc0, 0, 0, 0); \
    acc1 = MFMA_BF16(ah10, bh##S##0, acc1, 0, 0, 0); \
    acc1 = MFMA_BF16(al10, bh##S##0, acc1, 0, 0, 0); \
    acc1 = MFMA_BF16(ah10, bl##S##0, acc1, 0, 0, 0); \
    acc0 = MFMA_BF16(ah01, bh##S##1, acc0, 0, 0, 0); \
    acc0 = MFMA_BF16(al01, bh##S##1, acc0, 0, 0, 0); \
    acc0 = MFMA_BF16(ah01, bl##S##1, acc0, 0, 0, 0); \
    acc1 = MFMA_BF16(ah11, bh##S##1, acc1, 0, 0, 0); \
    acc1 = MFMA_BF16(al11, bh##S##1, acc1, 0, 0, 0); \
    acc1 = MFMA_BF16(ah11, bl##S##1, acc1, 0, 0, 0); \
    acc0 = MFMA_BF16(ah02, bh##S##2, acc0, 0, 0, 0); \
    acc0 = MFMA_BF16(al02, bh##S##2, acc0, 0, 0, 0); \
    acc0 = MFMA_BF16(ah02, bl##S##2, acc0, 0, 0, 0); \
    acc1 = MFMA_BF16(ah12, bh##S##2, acc1, 0, 0, 0); \
    acc1 = MFMA_BF16(al12, bh##S##2, acc1, 0, 0, 0); \
    acc1 = MFMA_BF16(ah12, bl##S##2, acc1, 0, 0, 0); \
    acc0 = MFMA_BF16(ah03, bh##S##3, acc0, 0, 0, 0); \
    acc0 = MFMA_BF16(al03, bh##S##3, acc0, 0, 0, 0); \
    acc0 = MFMA_BF16(ah03, bl##S##3, acc0, 0, 0, 0); \
    acc1 = MFMA_BF16(ah13, bh##S##3, acc1, 0, 0, 0); \
    acc1 = MFMA_BF16(al13, bh##S##3, acc1, 0, 0, 0); \
    acc1 = MFMA_BF16(ah13, bl##S##3, acc1, 0, 0, 0); \
    const float cqv = cqv##S; \
    const int   kc  = (kt) * 16 + ln; \
    SLOTS(UPD) }

#define UPD(g,r) { \
    float s_ = fmaf(-2.0f, (g ? acc1 : acc0)[r], cqv); \
    bool c1_ = s_ < v1_##g##r; \
    bool c2_ = s_ < v2_##g##r; \
    v2_##g##r = c1_ ? v1_##g##r : (c2_ ? s_ : v2_##g##r); \
    k2_##g##r = c1_ ? k1_##g##r : (c2_ ? kc : k2_##g##r); \
    v1_##g##r = c1_ ? s_ : v1_##g##r; \
    k1_##g##r = c1_ ? kc : k1_##g##r; }

    DECL_B(A) DECL_B(B)
    LOAD_B(A, 0);
    #pragma unroll 1
    for (int kt = 0; kt < NKT; kt += 2) {
        LOAD_B(B, kt + 1);             // in flight under COMPUTE A
        COMPUTE_B(A, kt);
        if (kt + 2 < NKT) LOAD_B(A, kt + 2);   // in flight under COMPUTE B
        COMPUTE_B(B, kt + 1);
    }
#undef UPD
#undef COMPUTE_B
#undef LOAD_B
#undef DECL_B

    // ---- butterfly merge across the 16 lanes of each col-group ----
    for (int m_ = 1; m_ <= 8; m_ <<= 1) {
#define MRG(g,r) { \
        float ov1 = __shfl_xor(v1_##g##r, m_, 16); int ok1 = __shfl_xor(k1_##g##r, m_, 16); \
        float ov2 = __shfl_xor(v2_##g##r, m_, 16); int ok2 = __shfl_xor(k2_##g##r, m_, 16); \
        if (ov1 < v1_##g##r || (ov1 == v1_##g##r && ok1 < k1_##g##r)) { \
            if (v1_##g##r < ov2 || (v1_##g##r == ov2 && k1_##g##r < ok2)) { v2_##g##r = v1_##g##r; k2_##g##r = k1_##g##r; } \
            else { v2_##g##r = ov2; k2_##g##r = ok2; } \
            v1_##g##r = ov1; k1_##g##r = ok1; \
        } else if (ov1 < v2_##g##r || (ov1 == v2_##g##r && ok1 < k2_##g##r)) { \
            v2_##g##r = ov1; k2_##g##r = ok1; \
        } }
        SLOTS(MRG)
#undef MRG
    }
    if (ln == 0) {
#define WRT(g,r) { int rloc = w * 32 + g * 16 + quad * 4 + r; \
        s_v1[rloc] = v1_##g##r; s_v2[rloc] = v2_##g##r; \
        s_k1[rloc] = k1_##g##r; s_k2[rloc] = k2_##g##r; }
        SLOTS(WRT)
#undef WRT
    }
    __syncthreads();

    // ---- per-row finalize: fp32 R1-order distance + fp64 near-tie re-decide ----
    if (t < ROWS_PB) {
        int rowg = rowblock + t;
        const bool valid = rowg < rows;
        rowg = valid ? rowg : rows - 1;
        float v1 = s_v1[t], v2 = s_v2[t];
        int k1 = s_k1[t], k2 = s_k2[t];
        const float* xr = x + (size_t)rowg * C;

        // rs in R1 float4 order
        float sx = 0.f, sy = 0.f, sz = 0.f, sw = 0.f;
        {
            const float4* xp = (const float4*)xr;
            #pragma unroll
            for (int i = 0; i < C / 4; ++i) {
                float4 v = xp[i];
                sx += v.x * v.x; sy += v.y * v.y;
                sz += v.z * v.z; sw += v.w * v.w;
            }
        }
        const float rs = (sx + sy) + (sz + sw);

        bool switched = false;
        double qwin = 0.0;
        if (v2 - v1 < EPS_TRIG) {
            const float* c1p = cb + (size_t)k1 * C;
            const float* c2p = cb + (size_t)k2 * C;
            double dot1 = 0.0, cq1 = 0.0, dot2 = 0.0, cq2 = 0.0;
            #pragma unroll 8
            for (int c = 0; c < C; ++c) {
                const double xc  = (double)xr[c];
                const double cv1 = (double)c1p[c];
                const double cv2 = (double)c2p[c];
                dot1 += xc * cv1;  cq1 += cv1 * cv1;
                dot2 += xc * cv2;  cq2 += cv2 * cv2;
            }
            const double q1 = cq1 - 2.0 * dot1;
            const double q2 = cq2 - 2.0 * dot2;
            if (q2 < q1 || (q2 == q1 && k2 < k1)) { k1 = k2; switched = true; qwin = q2; }
        }

        // exact fp32 distance for the final k1 (R1 chain order)
        const float* c1p = cb + (size_t)k1 * C;
        float a = 0.f;
        #pragma unroll 16
        for (int c = 0; c < C; ++c) a = fmaf(xr[c], c1p[c], a);
        float d = (rs + cq[k1]) - 2.f * a;
        if (switched) d = (float)((double)rs + qwin);

        if (valid) {
            out_fidx[rowg] = (float)k1;
            out_idx[rowg]  = (float)k1;
            out_dist[rowg] = d;
        }
        s_k1[t] = k1;   // final index for the gather
    }
    __syncthreads();

    // ---- gather codes: 2 threads per row ----
    {
        const int r    = t >> 1;
        const int half = t & 1;
        const int rowg = rowblock + r;
        if (rowg < rows) {
            const int k1 = s_k1[r];
            const float4* src = (const float4*)(cb + (size_t)k1 * C) + half * 16;
            float4*       dst = (float4*)(out_codes + (size_t)rowg * C) + half * 16;
            #pragma unroll
            for (int i = 0; i < 16; ++i) dst[i] = src[i];
        }
    }
}

// ---------------- fallback (R1 kernel, needs no workspace) ----------------
__global__ __launch_bounds__(TPB, 1)
void vq_nearest_fallback(const float* __restrict__ x,
                         const float* __restrict__ cb,
                         float* __restrict__ out_codes,
                         float* __restrict__ out_fidx,
                         float* __restrict__ out_idx,
                         float* __restrict__ out_dist,
                         int rows)
{
    __shared__ float s_cbsq[KCODES];
    const int t = threadIdx.x;
    for (int k = t; k < KCODES; k += TPB) {
        const float4* cp = (const float4*)(cb + (size_t)k * C);
        float sx = 0.f, sy = 0.f, sz = 0.f, sw = 0.f;
        #pragma unroll
        for (int i = 0; i < C / 4; ++i) {
            float4 v = cp[i];
            sx += v.x * v.x; sy += v.y * v.y; sz += v.z * v.z; sw += v.w * v.w;
        }
        s_cbsq[k] = (sx + sy) + (sz + sw);
    }
    __syncthreads();
    const int row = blockIdx.x * TPB + t;
    if (row >= rows) return;
    float xr[C];
    {
        const float4* xp = (const float4*)(x + (size_t)row * C);
        #pragma unroll
        for (int i = 0; i < C / 4; ++i) {
            float4 v = xp[i];
            xr[4*i+0] = v.x; xr[4*i+1] = v.y; xr[4*i+2] = v.z; xr[4*i+3] = v.w;
        }
    }
    float rs;
    {
        float sx = 0.f, sy = 0.f, sz = 0.f, sw = 0.f;
        #pragma unroll
        for (int i = 0; i < C / 4; ++i) {
            sx += xr[4*i+0]*xr[4*i+0]; sy += xr[4*i+1]*xr[4*i+1];
            sz += xr[4*i+2]*xr[4*i+2]; sw += xr[4*i+3]*xr[4*i+3];
        }
        rs = (sx + sy) + (sz + sw);
    }
    float v1 = INFINITY, v2 = INFINITY; int k1 = 0, k2 = 0;
    #pragma unroll 1
    for (int k0 = 0; k0 < KCODES; k0 += 4) {
        const float* c0 = cb + (size_t)k0 * C;
        float a0 = 0.f, a1 = 0.f, a2 = 0.f, a3 = 0.f;
        #pragma unroll
        for (int c = 0; c < C; ++c) {
            const float xc = xr[c];
            a0 = fmaf(xc, c0[c], a0);
            a1 = fmaf(xc, c0[C + c], a1);
            a2 = fmaf(xc, c0[2*C + c], a2);
            a3 = fmaf(xc, c0[3*C + c], a3);
        }
        const float d0 = (rs + s_cbsq[k0+0]) - 2.f * a0;
        const float d1 = (rs + s_cbsq[k0+1]) - 2.f * a1;
        const float d2 = (rs + s_cbsq[k0+2]) - 2.f * a2;
        const float d3 = (rs + s_cbsq[k0+3]) - 2.f * a3;
        #define UPDF(dv, ki)                                                 \
            if ((dv) < v1)      { v2 = v1; k2 = k1; v1 = (dv); k1 = (ki); } \
            else if ((dv) < v2) { v2 = (dv); k2 = (ki); }
        UPDF(d0, k0+0); UPDF(d1, k0+1); UPDF(d2, k0+2); UPDF(d3, k0+3);
        #undef UPDF
    }
    if (v2 - v1 < 0.125f) {
        const float* c1p = cb + (size_t)k1 * C;
        const float* c2p = cb + (size_t)k2 * C;
        double dot1 = 0.0, cq1 = 0.0, dot2 = 0.0, cq2 = 0.0;
        #pragma unroll 8
        for (int c = 0; c < C; ++c) {
            const double xc = (double)xr[c];
            const double cv1 = (double)c1p[c];
            const double cv2 = (double)c2p[c];
            dot1 += xc * cv1; cq1 += cv1 * cv1;
            dot2 += xc * cv2; cq2 += cv2 * cv2;
        }
        const double q1 = cq1 - 2.0 * dot1;
        const double q2 = cq2 - 2.0 * dot2;
        if (q2 < q1 || (q2 == q1 && k2 < k1)) { k1 = k2; v1 = (float)((double)rs + q2); }
    }
    {
        const float4* src = (const float4*)(cb + (size_t)k1 * C);
        float4* dst = (float4*)(out_codes + (size_t)row * C);
        #pragma unroll
        for (int i = 0; i < C / 4; ++i) dst[i] = src[i];
        out_fidx[row] = (float)k1;
        out_idx[row]  = (float)k1;
        out_dist[row] = v1;
    }
}

extern "C" void kernel_launch(void* const* d_in, const int* in_sizes, int n_in,
                              void* d_out, int out_size, void* d_ws, size_t ws_size,
                              hipStream_t stream) {
    const float* x  = (const float*)d_in[0];
    const float* cb = (const float*)d_in[1];
    const int rows = in_sizes[0] / C;   // 65536

    float* out       = (float*)d_out;
    float* out_codes = out;                          // rows*C
    float* out_fidx  = out + (size_t)rows * C;       // rows
    float* out_idx   = out_fidx + rows;              // rows
    float* out_dist  = out_idx + rows;               // rows

    // workspace layout
    const size_t cbh_off = 0;
    const size_t cbl_off = (size_t)KCODES * C * sizeof(uint16_t);      // 256 KB
    const size_t cq_off  = cbl_off * 2;                                // 512 KB
    const size_t need    = cq_off + KCODES * sizeof(float);

    if (ws_size >= need) {
        uint16_t* cbh = (uint16_t*)((char*)d_ws + cbh_off);
        uint16_t* cbl = (uint16_t*)((char*)d_ws + cbl_off);
        float*    cq  = (float*)((char*)d_ws + cq_off);

        cb_prep_kernel<<<(KCODES * C + TPB - 1) / TPB, TPB, 0, stream>>>(cb, cbh, cbl, cq);

        const int grid = (rows + ROWS_PB - 1) / ROWS_PB;   // 512
        vq_mfma_kernel<<<grid, TPB, 0, stream>>>(x, cb, cbh, cbl, cq,
                                                 out_codes, out_fidx, out_idx,
                                                 out_dist, rows);
    } else {
        const int rowblocks = (rows + TPB - 1) / TPB;
        vq_nearest_fallback<<<rowblocks, TPB, 0, stream>>>(x, cb, out_codes, out_fidx,
                                                           out_idx, out_dist, rows);
    }
}

// Round 7
// 184.695 us; speedup vs baseline: 1.9065x; 1.2933x over previous
//
#include <hip/hip_runtime.h>
#include <math.h>
#include <stdint.h>

#define C        128
#define KCODES   1024
#define TPB      256
#define ROWS_PB  128                  // rows per block
#define NCHUNK   64                   // codes per LDS chunk
#define NCHUNKS  (KCODES / NCHUNK)    // 16
#define BSTRIDE  272                  // padded row stride (bytes) = 128*2 + 16
#define BHALF    (NCHUNK * BSTRIDE)   // byte offset of the LO plane
#define EPS_TRIG 0.25f

typedef __attribute__((ext_vector_type(8))) short bf16x8_t;
typedef __attribute__((ext_vector_type(4))) float f32x4_t;

static __device__ __forceinline__ uint32_t bf16_rne(float f) {
    uint32_t u = __float_as_uint(f);
    return (u + 0x7FFFu + ((u >> 16) & 1u)) >> 16;
}
static __device__ __forceinline__ float bf16_hi_f(float f) {
    return __uint_as_float(bf16_rne(f) << 16);
}

// ============================================================================
// SINGLE-LAUNCH fused kernel (launch overhead measured ~20us/launch; 3->1).
//   - R1's proven LDS-staged chunk loop (the staging IS the coalescing
//     transform -- R6 proved direct-global B is L1-transaction-bound).
//   - Codebook fp32 -> bf16 hi/lo converted INLINE per chunk (R5-validated
//     numerics: coarse cq via 16-lane tree reduce only feeds top-2 selection;
//     near-tie fp64 re-decide + exact finalize protect the outputs).
//   - No workspace, no fences, no cross-block coordination (R5 lesson:
//     per-block device-scope fences flush L2 and are catastrophic).
// ============================================================================
#define SLOTS(OP) OP(0,0) OP(0,1) OP(0,2) OP(0,3) OP(1,0) OP(1,1) OP(1,2) OP(1,3)
#define MFMA_BF16 __builtin_amdgcn_mfma_f32_16x16x32_bf16

__global__ __launch_bounds__(TPB, 3)
void vq_fused_kernel(const float* __restrict__ x,
                     const float* __restrict__ cb,
                     float* __restrict__ out_codes,
                     float* __restrict__ out_fidx,
                     float* __restrict__ out_idx,
                     float* __restrict__ out_dist,
                     int rows)
{
    __shared__ __align__(16) uint8_t s_buf[2 * BHALF];   // 34816 B, also A-stage area
    __shared__ float s_cq[NCHUNK];
    __shared__ float s_v1[ROWS_PB], s_v2[ROWS_PB];
    __shared__ int   s_k1[ROWS_PB], s_k2[ROWS_PB];

    const int t    = threadIdx.x;
    const int lane = t & 63;
    const int w    = t >> 6;       // wave 0..3
    const int ln   = lane & 15;
    const int quad = lane >> 4;
    const int rowblock = blockIdx.x * ROWS_PB;

    // ---- stage x tile -> bf16 HI in s_buf (padded row-major) ----
    #pragma unroll 4
    for (int i = 0; i < 16; ++i) {
        int fid = t + i * TPB;            // float4 id in tile (4096)
        int row = fid >> 5;               // 0..127
        int kq  = fid & 31;               // float4 within row
        int grow = rowblock + row;
        grow = grow < rows ? grow : rows - 1;
        float4 v = ((const float4*)x)[(size_t)grow * 32 + kq];
        uint32_t p0 = bf16_rne(v.x) | (bf16_rne(v.y) << 16);
        uint32_t p1 = bf16_rne(v.z) | (bf16_rne(v.w) << 16);
        *(uint2*)(s_buf + row * BSTRIDE + kq * 8) = make_uint2(p0, p1);
    }
    __syncthreads();

    // ---- A-hi fragments -> registers (live for the whole kernel) ----
    const int arow0 = (w * 32 + ln) * BSTRIDE;        // rowgroup 0
    const int arow1 = (w * 32 + 16 + ln) * BSTRIDE;   // rowgroup 1
    bf16x8_t ah00, ah01, ah02, ah03, ah10, ah11, ah12, ah13;
    ah00 = *(const bf16x8_t*)(s_buf + arow0 + 0 * 64 + quad * 16);
    ah01 = *(const bf16x8_t*)(s_buf + arow0 + 1 * 64 + quad * 16);
    ah02 = *(const bf16x8_t*)(s_buf + arow0 + 2 * 64 + quad * 16);
    ah03 = *(const bf16x8_t*)(s_buf + arow0 + 3 * 64 + quad * 16);
    ah10 = *(const bf16x8_t*)(s_buf + arow1 + 0 * 64 + quad * 16);
    ah11 = *(const bf16x8_t*)(s_buf + arow1 + 1 * 64 + quad * 16);
    ah12 = *(const bf16x8_t*)(s_buf + arow1 + 2 * 64 + quad * 16);
    ah13 = *(const bf16x8_t*)(s_buf + arow1 + 3 * 64 + quad * 16);
    __syncthreads();

    // ---- stage x tile -> bf16 LO ----
    #pragma unroll 4
    for (int i = 0; i < 16; ++i) {
        int fid = t + i * TPB;
        int row = fid >> 5;
        int kq  = fid & 31;
        int grow = rowblock + row;
        grow = grow < rows ? grow : rows - 1;
        float4 v = ((const float4*)x)[(size_t)grow * 32 + kq];
        uint32_t p0 = bf16_rne(v.x - bf16_hi_f(v.x)) | (bf16_rne(v.y - bf16_hi_f(v.y)) << 16);
        uint32_t p1 = bf16_rne(v.z - bf16_hi_f(v.z)) | (bf16_rne(v.w - bf16_hi_f(v.w)) << 16);
        *(uint2*)(s_buf + row * BSTRIDE + kq * 8) = make_uint2(p0, p1);
    }
    __syncthreads();

    bf16x8_t al00, al01, al02, al03, al10, al11, al12, al13;
    al00 = *(const bf16x8_t*)(s_buf + arow0 + 0 * 64 + quad * 16);
    al01 = *(const bf16x8_t*)(s_buf + arow0 + 1 * 64 + quad * 16);
    al02 = *(const bf16x8_t*)(s_buf + arow0 + 2 * 64 + quad * 16);
    al03 = *(const bf16x8_t*)(s_buf + arow0 + 3 * 64 + quad * 16);
    al10 = *(const bf16x8_t*)(s_buf + arow1 + 0 * 64 + quad * 16);
    al11 = *(const bf16x8_t*)(s_buf + arow1 + 1 * 64 + quad * 16);
    al12 = *(const bf16x8_t*)(s_buf + arow1 + 2 * 64 + quad * 16);
    al13 = *(const bf16x8_t*)(s_buf + arow1 + 3 * 64 + quad * 16);
    __syncthreads();

    // ---- per-lane top-2 state (8 row-slots) ----
#define DECL(g,r) float v1_##g##r = INFINITY, v2_##g##r = INFINITY; int k1_##g##r = 0, k2_##g##r = 0;
    SLOTS(DECL)
#undef DECL

    #pragma unroll 1
    for (int chn = 0; chn < NCHUNKS; ++chn) {
        const int kbase = chn * NCHUNK;
        // ---- stage B chunk from RAW fp32 codebook: convert bf16 hi/lo inline
        //      (bit-identical exprs to the old cb_prep_kernel) + coarse ||c||^2
        //      via 16-lane tree reduce (feeds top-2 selection only; near-tie
        //      re-decide + exact finalize protect outputs -- R5-validated). ----
        #pragma unroll
        for (int i = 0; i < 4; ++i) {
            int uid  = t + i * TPB;          // slot id (1024): code*16 + g
            int code = uid >> 4, g = uid & 15;
            const float4* src = (const float4*)(cb + (size_t)(kbase + code) * C) + g * 2;
            float4 v0 = src[0], v1 = src[1];
            uint32_t h0 = bf16_rne(v0.x) | (bf16_rne(v0.y) << 16);
            uint32_t h1 = bf16_rne(v0.z) | (bf16_rne(v0.w) << 16);
            uint32_t h2 = bf16_rne(v1.x) | (bf16_rne(v1.y) << 16);
            uint32_t h3 = bf16_rne(v1.z) | (bf16_rne(v1.w) << 16);
            uint32_t l0 = bf16_rne(v0.x - bf16_hi_f(v0.x)) | (bf16_rne(v0.y - bf16_hi_f(v0.y)) << 16);
            uint32_t l1 = bf16_rne(v0.z - bf16_hi_f(v0.z)) | (bf16_rne(v0.w - bf16_hi_f(v0.w)) << 16);
            uint32_t l2 = bf16_rne(v1.x - bf16_hi_f(v1.x)) | (bf16_rne(v1.y - bf16_hi_f(v1.y)) << 16);
            uint32_t l3 = bf16_rne(v1.z - bf16_hi_f(v1.z)) | (bf16_rne(v1.w - bf16_hi_f(v1.w)) << 16);
            *(uint4*)(s_buf + code * BSTRIDE + g * 16)          = make_uint4(h0, h1, h2, h3);
            *(uint4*)(s_buf + BHALF + code * BSTRIDE + g * 16)  = make_uint4(l0, l1, l2, l3);
            float ps = ((v0.x * v0.x + v0.y * v0.y) + (v0.z * v0.z + v0.w * v0.w))
                     + ((v1.x * v1.x + v1.y * v1.y) + (v1.z * v1.z + v1.w * v1.w));
            ps += __shfl_xor(ps, 1, 16);
            ps += __shfl_xor(ps, 2, 16);
            ps += __shfl_xor(ps, 4, 16);
            ps += __shfl_xor(ps, 8, 16);
            if (g == 0) s_cq[code] = ps;
        }
        __syncthreads();

        const uint8_t* bbase = s_buf + (size_t)ln * BSTRIDE + quad * 16;
        #pragma unroll
        for (int ct = 0; ct < 4; ++ct) {
            const uint8_t* bh_p = bbase + (size_t)ct * 16 * BSTRIDE;
            const uint8_t* bl_p = bh_p + BHALF;
            f32x4_t acc0 = {0.f, 0.f, 0.f, 0.f};
            f32x4_t acc1 = {0.f, 0.f, 0.f, 0.f};
#define KSTEP(kk) { \
            bf16x8_t bh = *(const bf16x8_t*)(bh_p + kk * 64); \
            bf16x8_t bl = *(const bf16x8_t*)(bl_p + kk * 64); \
            acc0 = MFMA_BF16(ah0##kk, bh, acc0, 0, 0, 0); \
            acc0 = MFMA_BF16(al0##kk, bh, acc0, 0, 0, 0); \
            acc0 = MFMA_BF16(ah0##kk, bl, acc0, 0, 0, 0); \
            acc1 = MFMA_BF16(ah1##kk, bh, acc1, 0, 0, 0); \
            acc1 = MFMA_BF16(al1##kk, bh, acc1, 0, 0, 0); \
            acc1 = MFMA_BF16(ah1##kk, bl, acc1, 0, 0, 0); }
            KSTEP(0) KSTEP(1) KSTEP(2) KSTEP(3)
#undef KSTEP
            const float cqv = s_cq[ct * 16 + ln];
            const int   kc  = kbase + ct * 16 + ln;
#define UPD(g,r) { \
            float s_ = fmaf(-2.0f, (g ? acc1 : acc0)[r], cqv); \
            bool c1_ = s_ < v1_##g##r; \
            bool c2_ = s_ < v2_##g##r; \
            v2_##g##r = c1_ ? v1_##g##r : (c2_ ? s_ : v2_##g##r); \
            k2_##g##r = c1_ ? k1_##g##r : (c2_ ? kc : k2_##g##r); \
            v1_##g##r = c1_ ? s_ : v1_##g##r; \
            k1_##g##r = c1_ ? kc : k1_##g##r; }
            SLOTS(UPD)
#undef UPD
        }
        __syncthreads();
    }

    // ---- butterfly merge across the 16 lanes of each col-group ----
    for (int m_ = 1; m_ <= 8; m_ <<= 1) {
#define MRG(g,r) { \
        float ov1 = __shfl_xor(v1_##g##r, m_, 16); int ok1 = __shfl_xor(k1_##g##r, m_, 16); \
        float ov2 = __shfl_xor(v2_##g##r, m_, 16); int ok2 = __shfl_xor(k2_##g##r, m_, 16); \
        if (ov1 < v1_##g##r || (ov1 == v1_##g##r && ok1 < k1_##g##r)) { \
            if (v1_##g##r < ov2 || (v1_##g##r == ov2 && k1_##g##r < ok2)) { v2_##g##r = v1_##g##r; k2_##g##r = k1_##g##r; } \
            else { v2_##g##r = ov2; k2_##g##r = ok2; } \
            v1_##g##r = ov1; k1_##g##r = ok1; \
        } else if (ov1 < v2_##g##r || (ov1 == v2_##g##r && ok1 < k2_##g##r)) { \
            v2_##g##r = ov1; k2_##g##r = ok1; \
        } }
        SLOTS(MRG)
#undef MRG
    }
    if (ln == 0) {
#define WRT(g,r) { int rloc = w * 32 + g * 16 + quad * 4 + r; \
        s_v1[rloc] = v1_##g##r; s_v2[rloc] = v2_##g##r; \
        s_k1[rloc] = k1_##g##r; s_k2[rloc] = k2_##g##r; }
        SLOTS(WRT)
#undef WRT
    }
    __syncthreads();

    // ---- per-row finalize: fp32 R1-order distance + fp64 near-tie re-decide ----
    if (t < ROWS_PB) {
        int rowg = rowblock + t;
        const bool valid = rowg < rows;
        rowg = valid ? rowg : rows - 1;
        float v1 = s_v1[t], v2 = s_v2[t];
        int k1 = s_k1[t], k2 = s_k2[t];
        const float* xr = x + (size_t)rowg * C;

        // rs in R1 float4 order
        float sx = 0.f, sy = 0.f, sz = 0.f, sw = 0.f;
        {
            const float4* xp = (const float4*)xr;
            #pragma unroll
            for (int i = 0; i < C / 4; ++i) {
                float4 v = xp[i];
                sx += v.x * v.x; sy += v.y * v.y;
                sz += v.z * v.z; sw += v.w * v.w;
            }
        }
        const float rs = (sx + sy) + (sz + sw);

        bool switched = false;
        double qwin = 0.0;
        if (v2 - v1 < EPS_TRIG) {
            const float* c1p = cb + (size_t)k1 * C;
            const float* c2p = cb + (size_t)k2 * C;
            double dot1 = 0.0, cq1 = 0.0, dot2 = 0.0, cq2 = 0.0;
            #pragma unroll 8
            for (int c = 0; c < C; ++c) {
                const double xc  = (double)xr[c];
                const double cv1 = (double)c1p[c];
                const double cv2 = (double)c2p[c];
                dot1 += xc * cv1;  cq1 += cv1 * cv1;
                dot2 += xc * cv2;  cq2 += cv2 * cv2;
            }
            const double q1 = cq1 - 2.0 * dot1;
            const double q2 = cq2 - 2.0 * dot2;
            if (q2 < q1 || (q2 == q1 && k2 < k1)) { k1 = k2; switched = true; qwin = q2; }
        }

        // exact fp32 distance for the final k1 (R1 chain order) + inline
        // ||c_k1||^2 in the exact cbsq float4-chain order (bit-identical;
        // validated absmax 0.0 in R5)
        {
            const float4* c1p4 = (const float4*)(cb + (size_t)k1 * C);
            float a = 0.f;
            float qx = 0.f, qy = 0.f, qz = 0.f, qw = 0.f;
            #pragma unroll
            for (int i = 0; i < C / 4; ++i) {
                float4 cv = c1p4[i];
                float4 xv = ((const float4*)xr)[i];
                a = fmaf(xv.x, cv.x, a); a = fmaf(xv.y, cv.y, a);
                a = fmaf(xv.z, cv.z, a); a = fmaf(xv.w, cv.w, a);
                qx += cv.x * cv.x; qy += cv.y * cv.y;
                qz += cv.z * cv.z; qw += cv.w * cv.w;
            }
            float d = (rs + ((qx + qy) + (qz + qw))) - 2.f * a;
            if (switched) d = (float)((double)rs + qwin);

            if (valid) {
                out_fidx[rowg] = (float)k1;
                out_idx[rowg]  = (float)k1;
                out_dist[rowg] = d;
            }
        }
        s_k1[t] = k1;   // final index for the gather
    }
    __syncthreads();

    // ---- gather codes: 2 threads per row ----
    {
        const int r    = t >> 1;
        const int half = t & 1;
        const int rowg = rowblock + r;
        if (rowg < rows) {
            const int k1 = s_k1[r];
            const float4* src = (const float4*)(cb + (size_t)k1 * C) + half * 16;
            float4*       dst = (float4*)(out_codes + (size_t)rowg * C) + half * 16;
            #pragma unroll
            for (int i = 0; i < 16; ++i) dst[i] = src[i];
        }
    }
}

extern "C" void kernel_launch(void* const* d_in, const int* in_sizes, int n_in,
                              void* d_out, int out_size, void* d_ws, size_t ws_size,
                              hipStream_t stream) {
    const float* x  = (const float*)d_in[0];
    const float* cb = (const float*)d_in[1];
    const int rows = in_sizes[0] / C;   // 65536

    float* out       = (float*)d_out;
    float* out_codes = out;                          // rows*C
    float* out_fidx  = out + (size_t)rows * C;       // rows
    float* out_idx   = out_fidx + rows;              // rows
    float* out_dist  = out_idx + rows;               // rows

    const int grid = (rows + ROWS_PB - 1) / ROWS_PB;   // 512
    vq_fused_kernel<<<grid, TPB, 0, stream>>>(x, cb, out_codes, out_fidx,
                                              out_idx, out_dist, rows);
}